// Round 1
// baseline (409.159 us; speedup 1.0000x reference)
//
#include <hip/hip_runtime.h>
#include <math.h>

#define NN 512
#define NODE_D 256
#define EDGE_D 128
#define HN 8

#define SCALAR_SCALE 0.14433756729740643f   // (3*16)^-0.5
#define POINT_SCALE  0.13608276348795434f   // (3*4*4.5)^-0.5
#define PAIR_SCALE   0.5773502691896258f    // 3^-0.5

// workspace float offsets
#define OFF_QS 0
#define OFF_KS 65536
#define OFF_VS 131072
#define OFF_QP 196608
#define OFF_KP 245760
#define OFF_VP 294912
#define OFF_Q2 344064
#define OFF_K2 348160
#define OFF_FEAT 352256
// total floats: 352256 + 512*1280 = 1007616  (~3.85 MB)

// ---------------------------------------------------------------------------
// Kernel A: projections + rotations. 128 blocks x 256 thr, 4 rows per block.
// ---------------------------------------------------------------------------
__global__ __launch_bounds__(256) void k_proj(
    const float* __restrict__ node, const float* __restrict__ rotm,
    const float* __restrict__ trans,
    const float* __restrict__ Wsq, const float* __restrict__ Wsk, const float* __restrict__ Wsv,
    const float* __restrict__ Wpq, const float* __restrict__ Wpk, const float* __restrict__ Wpv,
    float* __restrict__ ws)
{
  __shared__ float node_l[4][256];
  __shared__ float p_l[4][288];   // pq|pk|pv (96 each) per row
  __shared__ float r_l[4][288];   // rotated
  const int t = threadIdx.x;
  const int n0 = blockIdx.x * 4;

  #pragma unroll
  for (int q = 0; q < 4; ++q) {
    int f = t + q * 256;
    node_l[f >> 8][f & 255] = node[(size_t)(n0 + (f >> 8)) * 256 + (f & 255)];
  }
  __syncthreads();

  for (int idx = t; idx < 672; idx += 256) {
    const float* W; int col, ncol, arr;
    if (idx < 384) { arr = idx >> 7; col = idx & 127; ncol = 128;
                     W = (arr == 0) ? Wsq : (arr == 1) ? Wsk : Wsv; }
    else { int p = idx - 384; arr = 3 + p / 96; col = p % 96; ncol = 96;
           W = (arr == 3) ? Wpq : (arr == 4) ? Wpk : Wpv; }
    float a0 = 0.f, a1 = 0.f, a2 = 0.f, a3 = 0.f;
    #pragma unroll 8
    for (int k = 0; k < 256; ++k) {
      float w = W[(size_t)k * ncol + col];
      a0 += node_l[0][k] * w; a1 += node_l[1][k] * w;
      a2 += node_l[2][k] * w; a3 += node_l[3][k] * w;
    }
    if (arr < 3) {
      float* dst = ws + ((arr == 0) ? OFF_QS : (arr == 1) ? OFF_KS : OFF_VS);
      dst[(size_t)(n0 + 0) * 128 + col] = a0;
      dst[(size_t)(n0 + 1) * 128 + col] = a1;
      dst[(size_t)(n0 + 2) * 128 + col] = a2;
      dst[(size_t)(n0 + 3) * 128 + col] = a3;
    } else {
      int a = arr - 3;
      p_l[0][a * 96 + col] = a0; p_l[1][a * 96 + col] = a1;
      p_l[2][a * 96 + col] = a2; p_l[3][a * 96 + col] = a3;
    }
  }
  __syncthreads();

  // rotate: out[h][d][r] = sum_c p[h][d][c]*R[r][c] + t[r]
  for (int idx = t; idx < 1152; idx += 256) {
    int row = idx / 288, rem = idx % 288;
    int a = rem / 96, col = rem % 96;
    int rr = col % 3;
    int n = n0 + row;
    const float* R = rotm + (size_t)(n * 3 + rr) * 3;
    const float* P = &p_l[row][a * 96 + (col - rr)];
    float val = P[0] * R[0] + P[1] * R[1] + P[2] * R[2] + trans[n * 3 + rr];
    r_l[row][a * 96 + col] = val;
    float* dst = ws + ((a == 0) ? OFF_QP : (a == 1) ? OFF_KP : OFF_VP);
    dst[(size_t)n * 96 + col] = val;
  }
  __syncthreads();

  if (t < 64) {
    int row = t >> 4, rem = t & 15;
    int which = rem >> 3, h = rem & 7;
    const float* src = &r_l[row][which * 96 + h * 12];
    float s = 0.f;
    #pragma unroll
    for (int m = 0; m < 12; ++m) s += src[m] * src[m];
    int n = n0 + row;
    ws[((which == 0) ? OFF_Q2 : OFF_K2) + n * 8 + h] = s;
  }
}

// ---------------------------------------------------------------------------
// Kernel B: fused attention per query row. 512 blocks x 256 thr.
// ---------------------------------------------------------------------------
#define LGS 516
__global__ __launch_bounds__(256) void k_attn(
    const float* __restrict__ edge, const float* __restrict__ pw_in,
    const float* __restrict__ Wpb, const float* __restrict__ bpb,
    const float* __restrict__ rotm, const float* __restrict__ trans,
    const float* __restrict__ ws, float* __restrict__ feat)
{
  __shared__ float lg[8 * LGS];     // logits [h][j]; reused as reduction buffer
  __shared__ float attn[512 * 12];  // [j][12] (8 heads used, stride for banks/align)
  __shared__ float wpb_t[8 * 128];  // [h][d]
  __shared__ float qs_i[128];
  __shared__ float qp_i[96];
  __shared__ float q2_i[8];
  __shared__ float pw_s[8];
  __shared__ float bias_pb[8];

  const int t = threadIdx.x;
  const int i = blockIdx.x;
  const float* ksg = ws + OFF_KS;
  const float* vsg = ws + OFF_VS;
  const float* kpg = ws + OFF_KP;
  const float* vpg = ws + OFF_VP;
  const float* k2g = ws + OFF_K2;

  if (t < 128) qs_i[t] = (ws + OFF_QS)[(size_t)i * 128 + t];
  if (t < 96)  qp_i[t] = (ws + OFF_QP)[(size_t)i * 96 + t];
  if (t < 8) {
    q2_i[t] = (ws + OFF_Q2)[i * 8 + t];
    float x = pw_in[t];
    pw_s[t] = 0.5f * POINT_SCALE * logf(1.0f + expf(x));  // softplus
    bias_pb[t] = bpb[t];
  }
  #pragma unroll
  for (int q = 0; q < 4; ++q) {
    int f = t + q * 256;                 // f = h*128 + d
    wpb_t[f] = Wpb[(size_t)(f & 127) * 8 + (f >> 7)];
  }
  __syncthreads();

  // ---- phase 1: logits for all heads, per j ----
  for (int rep = 0; rep < 2; ++rep) {
    const int j = t + rep * 256;
    const float4* e4 = (const float4*)(edge + ((size_t)i * 512 + j) * 128);
    float pair[8] = {0,0,0,0,0,0,0,0};
    float sc[8]   = {0,0,0,0,0,0,0,0};
    float cr[8]   = {0,0,0,0,0,0,0,0};

    #pragma unroll
    for (int c = 0; c < 4; ++c) {        // 4 chunks of 32 d
      float4 ev[8];
      #pragma unroll
      for (int u = 0; u < 8; ++u) ev[u] = e4[c * 8 + u];
      #pragma unroll
      for (int h = 0; h < 8; ++h) {
        const float4* wv4 = (const float4*)&wpb_t[h * 128 + c * 32];
        #pragma unroll
        for (int u = 0; u < 8; ++u) {
          float4 wv = wv4[u];
          pair[h] += ev[u].x * wv.x + ev[u].y * wv.y + ev[u].z * wv.z + ev[u].w * wv.w;
        }
      }
    }
    const float4* ks4 = (const float4*)(ksg + (size_t)j * 128);
    const float4* qs4 = (const float4*)qs_i;
    #pragma unroll
    for (int h = 0; h < 8; ++h) {
      #pragma unroll
      for (int u = 0; u < 4; ++u) {
        float4 kv = ks4[h * 4 + u], qv = qs4[h * 4 + u];
        sc[h] += kv.x * qv.x + kv.y * qv.y + kv.z * qv.z + kv.w * qv.w;
      }
    }
    const float4* kp4 = (const float4*)(kpg + (size_t)j * 96);
    const float4* qp4 = (const float4*)qp_i;
    #pragma unroll
    for (int h = 0; h < 8; ++h) {
      #pragma unroll
      for (int u = 0; u < 3; ++u) {
        float4 kv = kp4[h * 3 + u], qv = qp4[h * 3 + u];
        cr[h] += kv.x * qv.x + kv.y * qv.y + kv.z * qv.z + kv.w * qv.w;
      }
    }
    const float* k2j = k2g + (size_t)j * 8;
    #pragma unroll
    for (int h = 0; h < 8; ++h) {
      float pd = q2_i[h] + k2j[h] - 2.0f * cr[h];
      lg[h * LGS + j] = sc[h] * SCALAR_SCALE + (pair[h] + bias_pb[h]) * PAIR_SCALE
                        - pw_s[h] * pd;
    }
  }
  __syncthreads();

  // ---- phase 2: softmax (2 heads per wave) ----
  {
    const int lane = t & 63, wid = t >> 6;
    #pragma unroll
    for (int hh = 0; hh < 2; ++hh) {
      int h = wid * 2 + hh;
      float m = -1e30f;
      for (int jj = lane; jj < 512; jj += 64) m = fmaxf(m, lg[h * LGS + jj]);
      #pragma unroll
      for (int s = 32; s; s >>= 1) m = fmaxf(m, __shfl_xor(m, s));
      float ss = 0.f;
      for (int jj = lane; jj < 512; jj += 64) {
        float p = __expf(lg[h * LGS + jj] - m);
        ss += p;
        attn[jj * 12 + h] = p;
      }
      #pragma unroll
      for (int s = 32; s; s >>= 1) ss += __shfl_xor(ss, s);
      float rinv = 1.0f / ss;
      for (int jj = lane; jj < 512; jj += 64) attn[jj * 12 + h] *= rinv;
    }
  }
  __syncthreads();

  float* frow = feat + (size_t)i * 1280;

  // ---- phase 3a: res_pair (coalesced second edge pass, 8 heads in regs) ----
  {
    const int d = t & 127, half = t >> 7;
    const float* ecol = edge + ((size_t)i * 512 + half * 256) * 128 + d;
    float acc[8] = {0,0,0,0,0,0,0,0};
    #pragma unroll 4
    for (int jj = 0; jj < 256; ++jj) {
      float e = ecol[(size_t)jj * 128];
      float4 a0 = *(const float4*)&attn[(half * 256 + jj) * 12];
      float4 a1 = *(const float4*)&attn[(half * 256 + jj) * 12 + 4];
      acc[0] += a0.x * e; acc[1] += a0.y * e; acc[2] += a0.z * e; acc[3] += a0.w * e;
      acc[4] += a1.x * e; acc[5] += a1.y * e; acc[6] += a1.z * e; acc[7] += a1.w * e;
    }
    #pragma unroll
    for (int h = 0; h < 8; ++h) lg[(half * 128 + d) * 8 + h] = acc[h];
  }
  __syncthreads();
  {
    #pragma unroll
    for (int q = 0; q < 4; ++q) {
      int idx = t + q * 256;            // h*128 + d
      int h = idx >> 7, d2 = idx & 127;
      frow[256 + idx] = lg[d2 * 8 + h] + lg[(128 + d2) * 8 + h];
    }
  }

  // ---- phase 3b: res_scalar (attn @ vs) ----
  {
    const int r = t & 127, half = t >> 7;
    const int h = r >> 4;
    float acc = 0.f;
    #pragma unroll 4
    for (int jj = 0; jj < 256; ++jj) {
      int j = half * 256 + jj;
      acc += attn[j * 12 + h] * vsg[(size_t)j * 128 + r];
    }
    lg[2048 + half * 128 + r] = acc;
  }
  // ---- phase 3c: res_pts raw (attn @ vp) ----
  if (t < 192) {
    const int half = (t < 96) ? 0 : 1;
    const int rr = t - half * 96;
    const int h = rr / 12;
    float acc = 0.f;
    #pragma unroll 4
    for (int jj = 0; jj < 256; ++jj) {
      int j = half * 256 + jj;
      acc += attn[j * 12 + h] * vpg[(size_t)j * 96 + rr];
    }
    lg[2304 + half * 96 + rr] = acc;
  }
  __syncthreads();

  if (t < 128) frow[t] = lg[2048 + t] + lg[2048 + 128 + t];
  if (t >= 128 && t < 224) {
    int rr = t - 128;
    lg[2496 + rr] = lg[2304 + rr] + lg[2304 + 96 + rr];  // o_p[h*12+d*3+r]
  }
  __syncthreads();

  // inverse rotation: res[c] = sum_r (o_p[r]-t[r]) * R[r][c]
  if (t < 96) {
    int c = t % 3;
    int base = t - c;
    const float* R = rotm + (size_t)(i * 3) * 3;
    float v0 = lg[2496 + base + 0] - trans[i * 3 + 0];
    float v1 = lg[2496 + base + 1] - trans[i * 3 + 1];
    float v2 = lg[2496 + base + 2] - trans[i * 3 + 2];
    float val = v0 * R[0 * 3 + c] + v1 * R[1 * 3 + c] + v2 * R[2 * 3 + c];
    lg[2592 + t] = val;
    frow[128 + t] = val;
  }
  __syncthreads();

  if (t < 32) {
    int b = t * 3;
    float x = lg[2592 + b], y = lg[2592 + b + 1], z = lg[2592 + b + 2];
    frow[224 + t] = sqrtf(x * x + y * y + z * z + 1e-8f);
  }
}

// ---------------------------------------------------------------------------
// Kernel C: out = feat(512x1280) @ W_out(1280x256) + b_out. 16x8 blocks.
// ---------------------------------------------------------------------------
__global__ __launch_bounds__(256) void k_out(
    const float* __restrict__ feat, const float* __restrict__ Wout,
    const float* __restrict__ bout, float* __restrict__ out)
{
  __shared__ float As[32 * 33];
  __shared__ float Bs[32 * 36];
  const int t = threadIdx.x;
  const int it = blockIdx.x, ot = blockIdx.y;
  const int row = t & 31, cb = (t >> 5) * 4;
  float4 acc = {0.f, 0.f, 0.f, 0.f};

  for (int kt = 0; kt < 40; ++kt) {
    __syncthreads();
    #pragma unroll
    for (int q = 0; q < 4; ++q) {
      int f = t + q * 256; int r = f >> 5, c = f & 31;
      As[r * 33 + c] = feat[(size_t)(it * 32 + r) * 1280 + kt * 32 + c];
      Bs[r * 36 + c] = Wout[(size_t)(kt * 32 + r) * 256 + ot * 32 + c];
    }
    __syncthreads();
    #pragma unroll
    for (int k = 0; k < 32; ++k) {
      float a = As[row * 33 + k];
      float4 b = *(const float4*)&Bs[k * 36 + cb];
      acc.x += a * b.x; acc.y += a * b.y; acc.z += a * b.z; acc.w += a * b.w;
    }
  }
  float4 bias = *(const float4*)&bout[ot * 32 + cb];
  float4 r;
  r.x = acc.x + bias.x; r.y = acc.y + bias.y;
  r.z = acc.z + bias.z; r.w = acc.w + bias.w;
  *(float4*)&out[(size_t)(it * 32 + row) * 256 + ot * 32 + cb] = r;
}

// ---------------------------------------------------------------------------
extern "C" void kernel_launch(void* const* d_in, const int* in_sizes, int n_in,
                              void* d_out, int out_size, void* d_ws, size_t ws_size,
                              hipStream_t stream) {
  const float* node  = (const float*)d_in[0];
  const float* edge  = (const float*)d_in[1];
  const float* rotm  = (const float*)d_in[2];
  const float* trans = (const float*)d_in[3];
  const float* Wsq   = (const float*)d_in[4];
  const float* Wsk   = (const float*)d_in[5];
  const float* Wsv   = (const float*)d_in[6];
  const float* Wpq   = (const float*)d_in[7];
  const float* Wpk   = (const float*)d_in[8];
  const float* Wpv   = (const float*)d_in[9];
  const float* pw    = (const float*)d_in[10];
  const float* Wpb   = (const float*)d_in[11];
  const float* bpb   = (const float*)d_in[12];
  const float* Wout  = (const float*)d_in[13];
  const float* bout  = (const float*)d_in[14];
  float* ws   = (float*)d_ws;
  float* out  = (float*)d_out;
  float* feat = ws + OFF_FEAT;

  k_proj<<<128, 256, 0, stream>>>(node, rotm, trans, Wsq, Wsk, Wsv, Wpq, Wpk, Wpv, ws);
  k_attn<<<512, 256, 0, stream>>>(edge, pw, Wpb, bpb, rotm, trans, ws, feat);
  k_out<<<dim3(16, 8), 256, 0, stream>>>(feat, Wout, bout, out);
}

// Round 2
// 259.079 us; speedup vs baseline: 1.5793x; 1.5793x over previous
//
#include <hip/hip_runtime.h>
#include <math.h>

#define NN 512
#define NODE_D 256
#define EDGE_D 128
#define HN 8

#define SCALAR_SCALE 0.14433756729740643f   // (3*16)^-0.5
#define POINT_SCALE  0.13608276348795434f   // (3*4*4.5)^-0.5
#define PAIR_SCALE   0.5773502691896258f    // 3^-0.5

// workspace float offsets
#define OFF_QS 0
#define OFF_KS 65536
#define OFF_VS 131072
#define OFF_QP 196608
#define OFF_KP 245760
#define OFF_VP 294912
#define OFF_Q2 344064
#define OFF_K2 348160
#define OFF_FEAT 352256
// PRAW (512x288 raw point projections) aliases FEAT: consumed by k_rot before
// k_attn writes feat. total floats: 352256 + 512*1280 = 1007616 (~3.85 MB)
#define OFF_PRAW OFF_FEAT

// ---------------------------------------------------------------------------
// Kernel A1: Y(512x672) = node(512x256) @ [Wsq|Wsk|Wsv|Wpq|Wpk|Wpv].
// 32x32 tiles, grid (16,21). Every 32-col tile sits inside one W array.
// ---------------------------------------------------------------------------
__global__ __launch_bounds__(256) void k_projgemm(
    const float* __restrict__ node,
    const float* __restrict__ Wsq, const float* __restrict__ Wsk, const float* __restrict__ Wsv,
    const float* __restrict__ Wpq, const float* __restrict__ Wpk, const float* __restrict__ Wpv,
    float* __restrict__ ws)
{
  __shared__ float As[32 * 33];
  __shared__ float Bs[32 * 36];
  const int t = threadIdx.x;
  const int it = blockIdx.x;       // row tile (32 rows)
  const int ct = blockIdx.y;       // col tile 0..20

  const float* W; int ncol, col0; float* dst; int ldd, dcol0;
  if (ct < 12) {
    int a = ct >> 2;               // 0=qs 1=ks 2=vs
    W = (a == 0) ? Wsq : (a == 1) ? Wsk : Wsv;
    ncol = 128; col0 = (ct & 3) * 32;
    dst = ws + ((a == 0) ? OFF_QS : (a == 1) ? OFF_KS : OFF_VS);
    ldd = 128; dcol0 = col0;
  } else {
    int p = ct - 12;
    int a = p / 3, cc = p % 3;     // a: 0=pq 1=pk 2=pv
    W = (a == 0) ? Wpq : (a == 1) ? Wpk : Wpv;
    ncol = 96; col0 = cc * 32;
    dst = ws + OFF_PRAW;
    ldd = 288; dcol0 = a * 96 + cc * 32;
  }

  const int row = t & 31, cb = (t >> 5) * 4;
  float4 acc = {0.f, 0.f, 0.f, 0.f};

  for (int kt = 0; kt < 8; ++kt) {
    __syncthreads();
    #pragma unroll
    for (int q = 0; q < 4; ++q) {
      int f = t + q * 256; int r = f >> 5, c = f & 31;
      As[r * 33 + c] = node[(size_t)(it * 32 + r) * 256 + kt * 32 + c];
      Bs[r * 36 + c] = W[(size_t)(kt * 32 + r) * ncol + col0 + c];
    }
    __syncthreads();
    #pragma unroll
    for (int k = 0; k < 32; ++k) {
      float a = As[row * 33 + k];
      float4 b = *(const float4*)&Bs[k * 36 + cb];
      acc.x += a * b.x; acc.y += a * b.y; acc.z += a * b.z; acc.w += a * b.w;
    }
  }
  *(float4*)&dst[(size_t)(it * 32 + row) * ldd + dcol0 + cb] = acc;
}

// ---------------------------------------------------------------------------
// Kernel A2: rotate/translate point projections, q2/k2 norms.
// 128 blocks x 256 thr, 4 rows per block.
// ---------------------------------------------------------------------------
__global__ __launch_bounds__(256) void k_rot(
    const float* __restrict__ rotm, const float* __restrict__ trans,
    float* __restrict__ ws)
{
  __shared__ float p_l[4][288];
  __shared__ float r_l[4][288];
  const int t = threadIdx.x;
  const int n0 = blockIdx.x * 4;
  const float* praw = ws + OFF_PRAW;

  for (int idx = t; idx < 1152; idx += 256) {
    int row = idx / 288, rem = idx % 288;
    p_l[row][rem] = praw[(size_t)(n0 + row) * 288 + rem];
  }
  __syncthreads();

  // rotated[h][d][r] = sum_c p[h][d][c]*R[r][c] + t[r]
  for (int idx = t; idx < 1152; idx += 256) {
    int row = idx / 288, rem = idx % 288;
    int a = rem / 96, col = rem % 96;
    int rr = col % 3;
    int n = n0 + row;
    const float* R = rotm + (size_t)(n * 3 + rr) * 3;
    const float* P = &p_l[row][a * 96 + (col - rr)];
    float val = P[0] * R[0] + P[1] * R[1] + P[2] * R[2] + trans[n * 3 + rr];
    r_l[row][a * 96 + col] = val;
    float* dst = ws + ((a == 0) ? OFF_QP : (a == 1) ? OFF_KP : OFF_VP);
    dst[(size_t)n * 96 + col] = val;
  }
  __syncthreads();

  if (t < 64) {
    int row = t >> 4, rem = t & 15;
    int which = rem >> 3, h = rem & 7;
    const float* src = &r_l[row][which * 96 + h * 12];
    float s = 0.f;
    #pragma unroll
    for (int m = 0; m < 12; ++m) s += src[m] * src[m];
    int n = n0 + row;
    ws[((which == 0) ? OFF_Q2 : OFF_K2) + n * 8 + h] = s;
  }
}

// ---------------------------------------------------------------------------
// Kernel B: fused attention per query row. 512 blocks x 256 thr.
// ---------------------------------------------------------------------------
#define LGS 516
__global__ __launch_bounds__(256) void k_attn(
    const float* __restrict__ edge, const float* __restrict__ pw_in,
    const float* __restrict__ Wpb, const float* __restrict__ bpb,
    const float* __restrict__ rotm, const float* __restrict__ trans,
    const float* __restrict__ ws, float* __restrict__ feat)
{
  __shared__ float lg[8 * LGS];     // logits [h][j]; reused as reduction buffer
  __shared__ float attn[512 * 12];  // [j][12] (8 heads used, stride for banks/align)
  __shared__ float wpb_t[8 * 128];  // [h][d]
  __shared__ float qs_i[128];
  __shared__ float qp_i[96];
  __shared__ float q2_i[8];
  __shared__ float pw_s[8];
  __shared__ float bias_pb[8];

  const int t = threadIdx.x;
  const int i = blockIdx.x;
  const float* ksg = ws + OFF_KS;
  const float* vsg = ws + OFF_VS;
  const float* kpg = ws + OFF_KP;
  const float* vpg = ws + OFF_VP;
  const float* k2g = ws + OFF_K2;

  if (t < 128) qs_i[t] = (ws + OFF_QS)[(size_t)i * 128 + t];
  if (t < 96)  qp_i[t] = (ws + OFF_QP)[(size_t)i * 96 + t];
  if (t < 8) {
    q2_i[t] = (ws + OFF_Q2)[i * 8 + t];
    float x = pw_in[t];
    pw_s[t] = 0.5f * POINT_SCALE * logf(1.0f + expf(x));  // softplus
    bias_pb[t] = bpb[t];
  }
  #pragma unroll
  for (int q = 0; q < 4; ++q) {
    int f = t + q * 256;                 // f = h*128 + d
    wpb_t[f] = Wpb[(size_t)(f & 127) * 8 + (f >> 7)];
  }
  __syncthreads();

  // ---- phase 1: logits for all heads, per j ----
  for (int rep = 0; rep < 2; ++rep) {
    const int j = t + rep * 256;
    const float4* e4 = (const float4*)(edge + ((size_t)i * 512 + j) * 128);
    float pair[8] = {0,0,0,0,0,0,0,0};
    float sc[8]   = {0,0,0,0,0,0,0,0};
    float cr[8]   = {0,0,0,0,0,0,0,0};

    #pragma unroll
    for (int c = 0; c < 4; ++c) {        // 4 chunks of 32 d
      float4 ev[8];
      #pragma unroll
      for (int u = 0; u < 8; ++u) ev[u] = e4[c * 8 + u];
      #pragma unroll
      for (int h = 0; h < 8; ++h) {
        const float4* wv4 = (const float4*)&wpb_t[h * 128 + c * 32];
        #pragma unroll
        for (int u = 0; u < 8; ++u) {
          float4 wv = wv4[u];
          pair[h] += ev[u].x * wv.x + ev[u].y * wv.y + ev[u].z * wv.z + ev[u].w * wv.w;
        }
      }
    }
    const float4* ks4 = (const float4*)(ksg + (size_t)j * 128);
    const float4* qs4 = (const float4*)qs_i;
    #pragma unroll
    for (int h = 0; h < 8; ++h) {
      #pragma unroll
      for (int u = 0; u < 4; ++u) {
        float4 kv = ks4[h * 4 + u], qv = qs4[h * 4 + u];
        sc[h] += kv.x * qv.x + kv.y * qv.y + kv.z * qv.z + kv.w * qv.w;
      }
    }
    const float4* kp4 = (const float4*)(kpg + (size_t)j * 96);
    const float4* qp4 = (const float4*)qp_i;
    #pragma unroll
    for (int h = 0; h < 8; ++h) {
      #pragma unroll
      for (int u = 0; u < 3; ++u) {
        float4 kv = kp4[h * 3 + u], qv = qp4[h * 3 + u];
        cr[h] += kv.x * qv.x + kv.y * qv.y + kv.z * qv.z + kv.w * qv.w;
      }
    }
    const float* k2j = k2g + (size_t)j * 8;
    #pragma unroll
    for (int h = 0; h < 8; ++h) {
      float pd = q2_i[h] + k2j[h] - 2.0f * cr[h];
      lg[h * LGS + j] = sc[h] * SCALAR_SCALE + (pair[h] + bias_pb[h]) * PAIR_SCALE
                        - pw_s[h] * pd;
    }
  }
  __syncthreads();

  // ---- phase 2: softmax (2 heads per wave) ----
  {
    const int lane = t & 63, wid = t >> 6;
    #pragma unroll
    for (int hh = 0; hh < 2; ++hh) {
      int h = wid * 2 + hh;
      float m = -1e30f;
      for (int jj = lane; jj < 512; jj += 64) m = fmaxf(m, lg[h * LGS + jj]);
      #pragma unroll
      for (int s = 32; s; s >>= 1) m = fmaxf(m, __shfl_xor(m, s));
      float ss = 0.f;
      for (int jj = lane; jj < 512; jj += 64) {
        float p = __expf(lg[h * LGS + jj] - m);
        ss += p;
        attn[jj * 12 + h] = p;
      }
      #pragma unroll
      for (int s = 32; s; s >>= 1) ss += __shfl_xor(ss, s);
      float rinv = 1.0f / ss;
      for (int jj = lane; jj < 512; jj += 64) attn[jj * 12 + h] *= rinv;
    }
  }
  __syncthreads();

  float* frow = feat + (size_t)i * 1280;

  // ---- phase 3a: res_pair (coalesced second edge pass, 8 heads in regs) ----
  {
    const int d = t & 127, half = t >> 7;
    const float* ecol = edge + ((size_t)i * 512 + half * 256) * 128 + d;
    float acc[8] = {0,0,0,0,0,0,0,0};
    #pragma unroll 4
    for (int jj = 0; jj < 256; ++jj) {
      float e = ecol[(size_t)jj * 128];
      float4 a0 = *(const float4*)&attn[(half * 256 + jj) * 12];
      float4 a1 = *(const float4*)&attn[(half * 256 + jj) * 12 + 4];
      acc[0] += a0.x * e; acc[1] += a0.y * e; acc[2] += a0.z * e; acc[3] += a0.w * e;
      acc[4] += a1.x * e; acc[5] += a1.y * e; acc[6] += a1.z * e; acc[7] += a1.w * e;
    }
    #pragma unroll
    for (int h = 0; h < 8; ++h) lg[(half * 128 + d) * 8 + h] = acc[h];
  }
  __syncthreads();
  {
    #pragma unroll
    for (int q = 0; q < 4; ++q) {
      int idx = t + q * 256;            // h*128 + d
      int h = idx >> 7, d2 = idx & 127;
      frow[256 + idx] = lg[d2 * 8 + h] + lg[(128 + d2) * 8 + h];
    }
  }

  // ---- phase 3b: res_scalar (attn @ vs) ----
  {
    const int r = t & 127, half = t >> 7;
    const int h = r >> 4;
    float acc = 0.f;
    #pragma unroll 4
    for (int jj = 0; jj < 256; ++jj) {
      int j = half * 256 + jj;
      acc += attn[j * 12 + h] * vsg[(size_t)j * 128 + r];
    }
    lg[2048 + half * 128 + r] = acc;
  }
  // ---- phase 3c: res_pts raw (attn @ vp) ----
  if (t < 192) {
    const int half = (t < 96) ? 0 : 1;
    const int rr = t - half * 96;
    const int h = rr / 12;
    float acc = 0.f;
    #pragma unroll 4
    for (int jj = 0; jj < 256; ++jj) {
      int j = half * 256 + jj;
      acc += attn[j * 12 + h] * vpg[(size_t)j * 96 + rr];
    }
    lg[2304 + half * 96 + rr] = acc;
  }
  __syncthreads();

  if (t < 128) frow[t] = lg[2048 + t] + lg[2048 + 128 + t];
  if (t >= 128 && t < 224) {
    int rr = t - 128;
    lg[2496 + rr] = lg[2304 + rr] + lg[2304 + 96 + rr];  // o_p[h*12+d*3+r]
  }
  __syncthreads();

  // inverse rotation: res[c] = sum_r (o_p[r]-t[r]) * R[r][c]
  if (t < 96) {
    int c = t % 3;
    int base = t - c;
    const float* R = rotm + (size_t)(i * 3) * 3;
    float v0 = lg[2496 + base + 0] - trans[i * 3 + 0];
    float v1 = lg[2496 + base + 1] - trans[i * 3 + 1];
    float v2 = lg[2496 + base + 2] - trans[i * 3 + 2];
    float val = v0 * R[0 * 3 + c] + v1 * R[1 * 3 + c] + v2 * R[2 * 3 + c];
    lg[2592 + t] = val;
    frow[128 + t] = val;
  }
  __syncthreads();

  if (t < 32) {
    int b = t * 3;
    float x = lg[2592 + b], y = lg[2592 + b + 1], z = lg[2592 + b + 2];
    frow[224 + t] = sqrtf(x * x + y * y + z * z + 1e-8f);
  }
}

// ---------------------------------------------------------------------------
// Kernel C: out = feat(512x1280) @ W_out(1280x256) + b_out. 16x8 blocks.
// ---------------------------------------------------------------------------
__global__ __launch_bounds__(256) void k_out(
    const float* __restrict__ feat, const float* __restrict__ Wout,
    const float* __restrict__ bout, float* __restrict__ out)
{
  __shared__ float As[32 * 33];
  __shared__ float Bs[32 * 36];
  const int t = threadIdx.x;
  const int it = blockIdx.x, ot = blockIdx.y;
  const int row = t & 31, cb = (t >> 5) * 4;
  float4 acc = {0.f, 0.f, 0.f, 0.f};

  for (int kt = 0; kt < 40; ++kt) {
    __syncthreads();
    #pragma unroll
    for (int q = 0; q < 4; ++q) {
      int f = t + q * 256; int r = f >> 5, c = f & 31;
      As[r * 33 + c] = feat[(size_t)(it * 32 + r) * 1280 + kt * 32 + c];
      Bs[r * 36 + c] = Wout[(size_t)(kt * 32 + r) * 256 + ot * 32 + c];
    }
    __syncthreads();
    #pragma unroll
    for (int k = 0; k < 32; ++k) {
      float a = As[row * 33 + k];
      float4 b = *(const float4*)&Bs[k * 36 + cb];
      acc.x += a * b.x; acc.y += a * b.y; acc.z += a * b.z; acc.w += a * b.w;
    }
  }
  float4 bias = *(const float4*)&bout[ot * 32 + cb];
  float4 r;
  r.x = acc.x + bias.x; r.y = acc.y + bias.y;
  r.z = acc.z + bias.z; r.w = acc.w + bias.w;
  *(float4*)&out[(size_t)(it * 32 + row) * 256 + ot * 32 + cb] = r;
}

// ---------------------------------------------------------------------------
extern "C" void kernel_launch(void* const* d_in, const int* in_sizes, int n_in,
                              void* d_out, int out_size, void* d_ws, size_t ws_size,
                              hipStream_t stream) {
  const float* node  = (const float*)d_in[0];
  const float* edge  = (const float*)d_in[1];
  const float* rotm  = (const float*)d_in[2];
  const float* trans = (const float*)d_in[3];
  const float* Wsq   = (const float*)d_in[4];
  const float* Wsk   = (const float*)d_in[5];
  const float* Wsv   = (const float*)d_in[6];
  const float* Wpq   = (const float*)d_in[7];
  const float* Wpk   = (const float*)d_in[8];
  const float* Wpv   = (const float*)d_in[9];
  const float* pw    = (const float*)d_in[10];
  const float* Wpb   = (const float*)d_in[11];
  const float* bpb   = (const float*)d_in[12];
  const float* Wout  = (const float*)d_in[13];
  const float* bout  = (const float*)d_in[14];
  float* ws   = (float*)d_ws;
  float* out  = (float*)d_out;
  float* feat = ws + OFF_FEAT;

  k_projgemm<<<dim3(16, 21), 256, 0, stream>>>(node, Wsq, Wsk, Wsv, Wpq, Wpk, Wpv, ws);
  k_rot<<<128, 256, 0, stream>>>(rotm, trans, ws);
  k_attn<<<512, 256, 0, stream>>>(edge, pw, Wpb, bpb, rotm, trans, ws, feat);
  k_out<<<dim3(16, 8), 256, 0, stream>>>(feat, Wout, bout, out);
}

// Round 3
// 147.523 us; speedup vs baseline: 2.7735x; 1.7562x over previous
//
#include <hip/hip_runtime.h>
#include <hip/hip_fp16.h>
#include <math.h>

#define NN 512
#define NODE_D 256
#define EDGE_D 128
#define HN 8

#define SCALAR_SCALE 0.14433756729740643f   // (3*16)^-0.5
#define POINT_SCALE  0.13608276348795434f   // (3*4*4.5)^-0.5
#define PAIR_SCALE   0.5773502691896258f    // 3^-0.5

// workspace float offsets
#define OFF_QS 0
#define OFF_KS 65536
#define OFF_VS 131072
#define OFF_QP 196608
#define OFF_KP 245760
#define OFF_VP 294912
#define OFF_Q2 344064
#define OFF_K2 348160
#define OFF_FEAT 352256          // 512*1280
#define OFF_PRAW OFF_FEAT        // alias, consumed by k_rot before feat written
#define OFF_OUTP 1007616         // 4*512*256 floats k_out partials
#define OFF_LG16F 1531904        // fp16 logits region: 512*8*512 halfs = 4MB
// total ws bytes = 1531904*4 + 4194304 = 10321920 (~9.9 MB)

// ---------------------------------------------------------------------------
// Kernel A1: Y(512x672) = node @ [Wsq|Wsk|Wsv|Wpq|Wpk|Wpv]. grid (16,21).
// ---------------------------------------------------------------------------
__global__ __launch_bounds__(256) void k_projgemm(
    const float* __restrict__ node,
    const float* __restrict__ Wsq, const float* __restrict__ Wsk, const float* __restrict__ Wsv,
    const float* __restrict__ Wpq, const float* __restrict__ Wpk, const float* __restrict__ Wpv,
    float* __restrict__ ws)
{
  __shared__ float As[32 * 33];
  __shared__ float Bs[32 * 36];
  const int t = threadIdx.x;
  const int it = blockIdx.x;
  const int ct = blockIdx.y;

  const float* W; int ncol, col0; float* dst; int ldd, dcol0;
  if (ct < 12) {
    int a = ct >> 2;
    W = (a == 0) ? Wsq : (a == 1) ? Wsk : Wsv;
    ncol = 128; col0 = (ct & 3) * 32;
    dst = ws + ((a == 0) ? OFF_QS : (a == 1) ? OFF_KS : OFF_VS);
    ldd = 128; dcol0 = col0;
  } else {
    int p = ct - 12;
    int a = p / 3, cc = p % 3;
    W = (a == 0) ? Wpq : (a == 1) ? Wpk : Wpv;
    ncol = 96; col0 = cc * 32;
    dst = ws + OFF_PRAW;
    ldd = 288; dcol0 = a * 96 + cc * 32;
  }

  const int row = t & 31, cb = (t >> 5) * 4;
  float4 acc = {0.f, 0.f, 0.f, 0.f};

  for (int kt = 0; kt < 8; ++kt) {
    __syncthreads();
    #pragma unroll
    for (int q = 0; q < 4; ++q) {
      int f = t + q * 256; int r = f >> 5, c = f & 31;
      As[r * 33 + c] = node[(size_t)(it * 32 + r) * 256 + kt * 32 + c];
      Bs[r * 36 + c] = W[(size_t)(kt * 32 + r) * ncol + col0 + c];
    }
    __syncthreads();
    #pragma unroll
    for (int k = 0; k < 32; ++k) {
      float a = As[row * 33 + k];
      float4 b = *(const float4*)&Bs[k * 36 + cb];
      acc.x += a * b.x; acc.y += a * b.y; acc.z += a * b.z; acc.w += a * b.w;
    }
  }
  *(float4*)&dst[(size_t)(it * 32 + row) * ldd + dcol0 + cb] = acc;
}

// ---------------------------------------------------------------------------
// Kernel A2: rotate/translate points, q2/k2 norms. 128 blocks.
// ---------------------------------------------------------------------------
__global__ __launch_bounds__(256) void k_rot(
    const float* __restrict__ rotm, const float* __restrict__ trans,
    float* __restrict__ ws)
{
  __shared__ float p_l[4][288];
  __shared__ float r_l[4][288];
  const int t = threadIdx.x;
  const int n0 = blockIdx.x * 4;
  const float* praw = ws + OFF_PRAW;

  for (int idx = t; idx < 1152; idx += 256) {
    int row = idx / 288, rem = idx % 288;
    p_l[row][rem] = praw[(size_t)(n0 + row) * 288 + rem];
  }
  __syncthreads();

  for (int idx = t; idx < 1152; idx += 256) {
    int row = idx / 288, rem = idx % 288;
    int a = rem / 96, col = rem % 96;
    int rr = col % 3;
    int n = n0 + row;
    const float* R = rotm + (size_t)(n * 3 + rr) * 3;
    const float* P = &p_l[row][a * 96 + (col - rr)];
    float val = P[0] * R[0] + P[1] * R[1] + P[2] * R[2] + trans[n * 3 + rr];
    r_l[row][a * 96 + col] = val;
    float* dst = ws + ((a == 0) ? OFF_QP : (a == 1) ? OFF_KP : OFF_VP);
    dst[(size_t)n * 96 + col] = val;
  }
  __syncthreads();

  if (t < 64) {
    int row = t >> 4, rem = t & 15;
    int which = rem >> 3, h = rem & 7;
    const float* src = &r_l[row][which * 96 + h * 12];
    float s = 0.f;
    #pragma unroll
    for (int m = 0; m < 12; ++m) s += src[m] * src[m];
    int n = n0 + row;
    ws[((which == 0) ? OFF_Q2 : OFF_K2) + n * 8 + h] = s;
  }
}

// ---------------------------------------------------------------------------
// Kernel B1: logits for all (i,j,h) -> fp16. grid (2,512), thread = one (i,j).
// ---------------------------------------------------------------------------
__global__ __launch_bounds__(256, 2) void k_logits(
    const float* __restrict__ edge, const float* __restrict__ pw_in,
    const float* __restrict__ Wpb, const float* __restrict__ bpb,
    const float* __restrict__ ws, __half* __restrict__ lg16)
{
  __shared__ float wpb_l[128 * 8];   // [d][h], same layout as Wpb
  __shared__ float qs_l[128];
  __shared__ float qp_l[96];
  __shared__ float pw_l[8];
  __shared__ float cst_l[8];

  const int t = threadIdx.x;
  const int i = blockIdx.y;
  const int j = blockIdx.x * 256 + t;

  #pragma unroll
  for (int q = 0; q < 4; ++q) {
    int f = t + q * 256;
    wpb_l[f] = Wpb[f];
  }
  if (t < 128) qs_l[t] = (ws + OFF_QS)[(size_t)i * 128 + t];
  if (t < 96)  qp_l[t] = (ws + OFF_QP)[(size_t)i * 96 + t];
  if (t < 8) {
    float x = pw_in[t];
    float pwv = 0.5f * POINT_SCALE * logf(1.0f + expf(x));
    pw_l[t] = pwv;
    cst_l[t] = bpb[t] * PAIR_SCALE - pwv * (ws + OFF_Q2)[i * 8 + t];
  }
  __syncthreads();

  // pair dots (all 8 h) from streamed edge row
  float p[8] = {0,0,0,0,0,0,0,0};
  const float4* e4 = (const float4*)(edge + ((size_t)i * 512 + j) * 128);
  #pragma unroll
  for (int c = 0; c < 32; ++c) {
    float4 e = e4[c];
    #pragma unroll
    for (int dd = 0; dd < 4; ++dd) {
      float ev = (dd == 0) ? e.x : (dd == 1) ? e.y : (dd == 2) ? e.z : e.w;
      float4 wl = *(const float4*)&wpb_l[(c * 4 + dd) * 8];
      float4 wh = *(const float4*)&wpb_l[(c * 4 + dd) * 8 + 4];
      p[0] += ev * wl.x; p[1] += ev * wl.y; p[2] += ev * wl.z; p[3] += ev * wl.w;
      p[4] += ev * wh.x; p[5] += ev * wh.y; p[6] += ev * wh.z; p[7] += ev * wh.w;
    }
  }

  // scalar qk dots
  float sc[8] = {0,0,0,0,0,0,0,0};
  const float4* ks4 = (const float4*)(ws + OFF_KS + (size_t)j * 128);
  #pragma unroll
  for (int u = 0; u < 32; ++u) {
    float4 kv = ks4[u];
    float4 qv = *(const float4*)&qs_l[u * 4];
    sc[u >> 2] += kv.x * qv.x + kv.y * qv.y + kv.z * qv.z + kv.w * qv.w;
  }

  // point cross dots
  float cr[8] = {0,0,0,0,0,0,0,0};
  const float4* kp4 = (const float4*)(ws + OFF_KP + (size_t)j * 96);
  #pragma unroll
  for (int u = 0; u < 24; ++u) {
    float4 kv = kp4[u];
    float4 qv = *(const float4*)&qp_l[u * 4];
    cr[u / 3] += kv.x * qv.x + kv.y * qv.y + kv.z * qv.z + kv.w * qv.w;
  }

  const float* k2p = ws + OFF_K2 + (size_t)j * 8;
  #pragma unroll
  for (int h = 0; h < 8; ++h) {
    float lgv = sc[h] * SCALAR_SCALE + p[h] * PAIR_SCALE + cst_l[h]
              + pw_l[h] * (2.0f * cr[h] - k2p[h]);
    lg16[((size_t)i * 8 + h) * 512 + j] = __float2half(lgv);
  }
}

// ---------------------------------------------------------------------------
// Kernel B2: softmax + all attention-weighted outputs. 512 blocks (one per i).
// ---------------------------------------------------------------------------
__global__ __launch_bounds__(256) void k_attnout(
    const float* __restrict__ edge, const float* __restrict__ rotm,
    const float* __restrict__ trans, const float* __restrict__ ws,
    const __half* __restrict__ lg16, float* __restrict__ feat)
{
  __shared__ float aw[512 * 12];    // exp weights [j][12(8 used)]  24KB
  __shared__ float pl[8 * 128 * 8]; // pair partials [js][d][h]     32KB
  __shared__ float vsp[8 * 128];    // vs partials [js][col]         4KB
  __shared__ float vpp[8 * 96];     // vp partials [js][col]         3KB
  __shared__ float op_l[96];
  __shared__ float rp_l[96];
  __shared__ float linv_l[8];

  const int t = threadIdx.x;
  const int i = blockIdx.x;

  // ---- softmax (2 heads per wave), store unnormalized exp ----
  {
    const int lane = t & 63, wid = t >> 6;
    #pragma unroll
    for (int hh = 0; hh < 2; ++hh) {
      int h = wid * 2 + hh;
      const __half* lrow = lg16 + ((size_t)i * 8 + h) * 512;
      float x[8];
      float m = -1e30f;
      #pragma unroll
      for (int r = 0; r < 8; ++r) {
        x[r] = __half2float(lrow[lane + r * 64]);
        m = fmaxf(m, x[r]);
      }
      #pragma unroll
      for (int s = 32; s; s >>= 1) m = fmaxf(m, __shfl_xor(m, s));
      float ssum = 0.f;
      #pragma unroll
      for (int r = 0; r < 8; ++r) {
        float pv = __expf(x[r] - m);
        ssum += pv;
        aw[(lane + r * 64) * 12 + h] = pv;
      }
      #pragma unroll
      for (int s = 32; s; s >>= 1) ssum += __shfl_xor(ssum, s);
      if (lane == 0) linv_l[h] = 1.0f / ssum;
    }
  }
  __syncthreads();

  // ---- fused weighted sums: pair (4 d-cols x 8 h), vs (4 cols), vp (3 cols)
  const int dq = t & 31, js = t >> 5;         // j-octant js*64..+63
  const int b = dq >> 4;
  const int c0 = dq, c1 = dq + 32, c2 = dq + 64;     // vp cols
  const int h0 = c0 / 12, h1 = c1 / 12, h2 = c2 / 12;

  float4 aclo[4], achi[4];
  #pragma unroll
  for (int k = 0; k < 4; ++k) { aclo[k] = {0,0,0,0}; achi[k] = {0,0,0,0}; }
  float avs[4] = {0,0,0,0};
  float avp[3] = {0,0,0};

  const float* ebase = edge + (size_t)i * 512 * 128;
  const float* vsg = ws + OFF_VS;
  const float* vpg = ws + OFF_VP;

  for (int jj = 0; jj < 64; ++jj) {
    int j = js * 64 + jj;
    const float* er = ebase + (size_t)j * 128 + dq;
    const float* vr = vsg + (size_t)j * 128 + dq;
    const float* pr = vpg + (size_t)j * 96;
    float4 wlo = *(const float4*)&aw[j * 12];
    float4 whi = *(const float4*)&aw[j * 12 + 4];
    #pragma unroll
    for (int k = 0; k < 4; ++k) {
      float e = er[32 * k];
      aclo[k].x += wlo.x * e; aclo[k].y += wlo.y * e;
      aclo[k].z += wlo.z * e; aclo[k].w += wlo.w * e;
      achi[k].x += whi.x * e; achi[k].y += whi.y * e;
      achi[k].z += whi.z * e; achi[k].w += whi.w * e;
      float vv = vr[32 * k];
      float wk = (k == 0) ? (b ? wlo.y : wlo.x)
               : (k == 1) ? (b ? wlo.w : wlo.z)
               : (k == 2) ? (b ? whi.y : whi.x)
               :            (b ? whi.w : whi.z);
      avs[k] += wk * vv;
    }
    avp[0] += aw[j * 12 + h0] * pr[c0];
    avp[1] += aw[j * 12 + h1] * pr[c1];
    avp[2] += aw[j * 12 + h2] * pr[c2];
  }

  #pragma unroll
  for (int k = 0; k < 4; ++k) {
    int d = dq + 32 * k;
    *(float4*)&pl[(js * 128 + d) * 8] = aclo[k];
    *(float4*)&pl[(js * 128 + d) * 8 + 4] = achi[k];
    vsp[js * 128 + d] = avs[k];
  }
  vpp[js * 96 + c0] = avp[0];
  vpp[js * 96 + c1] = avp[1];
  vpp[js * 96 + c2] = avp[2];
  __syncthreads();

  float* frow = feat + (size_t)i * 1280;

  // ---- reduce pair partials: thread -> (d = t>>1, h-quad = (t&1)*4) ----
  {
    int d = t >> 1, hq = (t & 1) * 4;
    float4 s = {0,0,0,0};
    #pragma unroll
    for (int q = 0; q < 8; ++q) {
      float4 v = *(const float4*)&pl[(q * 128 + d) * 8 + hq];
      s.x += v.x; s.y += v.y; s.z += v.z; s.w += v.w;
    }
    frow[256 + (hq + 0) * 128 + d] = s.x * linv_l[hq + 0];
    frow[256 + (hq + 1) * 128 + d] = s.y * linv_l[hq + 1];
    frow[256 + (hq + 2) * 128 + d] = s.z * linv_l[hq + 2];
    frow[256 + (hq + 3) * 128 + d] = s.w * linv_l[hq + 3];
  }
  if (t < 128) {
    float s = 0.f;
    #pragma unroll
    for (int q = 0; q < 8; ++q) s += vsp[q * 128 + t];
    frow[t] = s * linv_l[t >> 4];
  }
  if (t < 96) {
    float s = 0.f;
    #pragma unroll
    for (int q = 0; q < 8; ++q) s += vpp[q * 96 + t];
    op_l[t] = s * linv_l[t / 12] - trans[i * 3 + (t % 3)];
  }
  __syncthreads();

  // inverse rotation: res[c] = sum_r op[base+r] * R[r][c]
  if (t < 96) {
    int c = t % 3, base = t - c;
    const float* R = rotm + (size_t)i * 9;
    float val = op_l[base] * R[c] + op_l[base + 1] * R[3 + c] + op_l[base + 2] * R[6 + c];
    rp_l[t] = val;
    frow[128 + t] = val;
  }
  __syncthreads();
  if (t < 32) {
    float x = rp_l[t * 3], y = rp_l[t * 3 + 1], z = rp_l[t * 3 + 2];
    frow[224 + t] = sqrtf(x * x + y * y + z * z + 1e-8f);
  }
}

// ---------------------------------------------------------------------------
// Kernel C1: k-split partial GEMM out_p[z] = feat[:, z*320:(z+1)*320] @ Wout
// grid (16, 8, 4)
// ---------------------------------------------------------------------------
__global__ __launch_bounds__(256) void k_outp(
    const float* __restrict__ feat, const float* __restrict__ Wout,
    float* __restrict__ ws)
{
  __shared__ float As[32 * 33];
  __shared__ float Bs[32 * 36];
  const int t = threadIdx.x;
  const int it = blockIdx.x, ot = blockIdx.y, z = blockIdx.z;
  const int row = t & 31, cb = (t >> 5) * 4;
  float4 acc = {0.f, 0.f, 0.f, 0.f};

  for (int kk = 0; kk < 10; ++kk) {
    int kt = z * 10 + kk;
    __syncthreads();
    #pragma unroll
    for (int q = 0; q < 4; ++q) {
      int f = t + q * 256; int r = f >> 5, c = f & 31;
      As[r * 33 + c] = feat[(size_t)(it * 32 + r) * 1280 + kt * 32 + c];
      Bs[r * 36 + c] = Wout[(size_t)(kt * 32 + r) * 256 + ot * 32 + c];
    }
    __syncthreads();
    #pragma unroll
    for (int k = 0; k < 32; ++k) {
      float a = As[row * 33 + k];
      float4 bv = *(const float4*)&Bs[k * 36 + cb];
      acc.x += a * bv.x; acc.y += a * bv.y; acc.z += a * bv.z; acc.w += a * bv.w;
    }
  }
  float* pc = ws + OFF_OUTP + (size_t)z * 131072;
  *(float4*)&pc[(size_t)(it * 32 + row) * 256 + ot * 32 + cb] = acc;
}

// ---------------------------------------------------------------------------
// Kernel C2: reduce partials + bias. grid 128 x 256 (float4 per thread).
// ---------------------------------------------------------------------------
__global__ __launch_bounds__(256) void k_outr(
    const float* __restrict__ ws, const float* __restrict__ bout,
    float* __restrict__ out)
{
  const int q = blockIdx.x * 256 + threadIdx.x;   // float4 index, 32768 total
  const float* pc = ws + OFF_OUTP;
  float4 a = *(const float4*)&pc[(size_t)q * 4];
  float4 b = *(const float4*)&pc[(size_t)q * 4 + 131072];
  float4 c = *(const float4*)&pc[(size_t)q * 4 + 262144];
  float4 d = *(const float4*)&pc[(size_t)q * 4 + 393216];
  float4 bias = *(const float4*)&bout[(q & 63) * 4];
  float4 r;
  r.x = a.x + b.x + c.x + d.x + bias.x;
  r.y = a.y + b.y + c.y + d.y + bias.y;
  r.z = a.z + b.z + c.z + d.z + bias.z;
  r.w = a.w + b.w + c.w + d.w + bias.w;
  *(float4*)&out[(size_t)q * 4] = r;
}

// ---------------------------------------------------------------------------
extern "C" void kernel_launch(void* const* d_in, const int* in_sizes, int n_in,
                              void* d_out, int out_size, void* d_ws, size_t ws_size,
                              hipStream_t stream) {
  const float* node  = (const float*)d_in[0];
  const float* edge  = (const float*)d_in[1];
  const float* rotm  = (const float*)d_in[2];
  const float* trans = (const float*)d_in[3];
  const float* Wsq   = (const float*)d_in[4];
  const float* Wsk   = (const float*)d_in[5];
  const float* Wsv   = (const float*)d_in[6];
  const float* Wpq   = (const float*)d_in[7];
  const float* Wpk   = (const float*)d_in[8];
  const float* Wpv   = (const float*)d_in[9];
  const float* pw    = (const float*)d_in[10];
  const float* Wpb   = (const float*)d_in[11];
  const float* bpb   = (const float*)d_in[12];
  const float* Wout  = (const float*)d_in[13];
  const float* bout  = (const float*)d_in[14];
  float* ws   = (float*)d_ws;
  float* out  = (float*)d_out;
  float* feat = ws + OFF_FEAT;
  __half* lg16 = (__half*)(ws + OFF_LG16F);

  k_projgemm<<<dim3(16, 21), 256, 0, stream>>>(node, Wsq, Wsk, Wsv, Wpq, Wpk, Wpv, ws);
  k_rot<<<128, 256, 0, stream>>>(rotm, trans, ws);
  k_logits<<<dim3(2, 512), 256, 0, stream>>>(edge, pw, Wpb, bpb, ws, lg16);
  k_attnout<<<512, 256, 0, stream>>>(edge, rotm, trans, ws, lg16, feat);
  k_outp<<<dim3(16, 8, 4), 256, 0, stream>>>(feat, Wout, ws);
  k_outr<<<128, 256, 0, stream>>>(ws, bout, out);
}

// Round 4
// 114.083 us; speedup vs baseline: 3.5865x; 1.2931x over previous
//
#include <hip/hip_runtime.h>
#include <hip/hip_fp16.h>
#include <math.h>

#define NN 512
#define NODE_D 256
#define EDGE_D 128
#define HN 8

#define SCALAR_SCALE 0.14433756729740643f   // (3*16)^-0.5
#define POINT_SCALE  0.13608276348795434f   // (3*4*4.5)^-0.5
#define PAIR_SCALE   0.5773502691896258f    // 3^-0.5

// workspace float offsets
#define OFF_QS   0            // 512x128
#define OFF_KS   65536        // 512x128
#define OFF_VS   131072       // 512x128
#define OFF_VP   196608       // 512x96
#define OFF_QCAT 245760       // 512x288
#define OFF_KCAT 393216       // 512x288
#define OFF_FEAT 540672       // 512x1280
#define OFF_PRAW OFF_FEAT     // 512x288 alias; consumed by k_rot2 before feat written
#define OFF_LG16 1196032      // float-offset of 512*512*8 halfs (4MB = 1048576 float-equiv)
#define OFF_OUTP 2244608      // 4*512*256 floats
// total ws = 2768896 floats = 11.08 MB

// ---------------------------------------------------------------------------
// Kernel A1: Y(512x672) = node @ [Wsq|Wsk|Wsv|Wpq|Wpk|Wpv]. grid (16,21).
// ---------------------------------------------------------------------------
__global__ __launch_bounds__(256) void k_projgemm(
    const float* __restrict__ node,
    const float* __restrict__ Wsq, const float* __restrict__ Wsk, const float* __restrict__ Wsv,
    const float* __restrict__ Wpq, const float* __restrict__ Wpk, const float* __restrict__ Wpv,
    float* __restrict__ ws)
{
  __shared__ float As[32 * 33];
  __shared__ float Bs[32 * 36];
  const int t = threadIdx.x;
  const int it = blockIdx.x;
  const int ct = blockIdx.y;

  const float* W; int ncol, col0; float* dst; int ldd, dcol0;
  if (ct < 12) {
    int a = ct >> 2;
    W = (a == 0) ? Wsq : (a == 1) ? Wsk : Wsv;
    ncol = 128; col0 = (ct & 3) * 32;
    dst = ws + ((a == 0) ? OFF_QS : (a == 1) ? OFF_KS : OFF_VS);
    ldd = 128; dcol0 = col0;
  } else {
    int p = ct - 12;
    int a = p / 3, cc = p % 3;
    W = (a == 0) ? Wpq : (a == 1) ? Wpk : Wpv;
    ncol = 96; col0 = cc * 32;
    dst = ws + OFF_PRAW;
    ldd = 288; dcol0 = a * 96 + cc * 32;
  }

  const int row = t & 31, cb = (t >> 5) * 4;
  float4 acc = {0.f, 0.f, 0.f, 0.f};

  for (int kt = 0; kt < 8; ++kt) {
    __syncthreads();
    #pragma unroll
    for (int q = 0; q < 4; ++q) {
      int f = t + q * 256; int r = f >> 5, c = f & 31;
      As[r * 33 + c] = node[(size_t)(it * 32 + r) * 256 + kt * 32 + c];
      Bs[r * 36 + c] = W[(size_t)(kt * 32 + r) * ncol + col0 + c];
    }
    __syncthreads();
    #pragma unroll
    for (int k = 0; k < 32; ++k) {
      float a = As[row * 33 + k];
      float4 b = *(const float4*)&Bs[k * 36 + cb];
      acc.x += a * b.x; acc.y += a * b.y; acc.z += a * b.z; acc.w += a * b.w;
    }
  }
  *(float4*)&dst[(size_t)(it * 32 + row) * ldd + dcol0 + cb] = acc;
}

// ---------------------------------------------------------------------------
// Kernel A2: rotate/translate points; build Qcat/Kcat (scales folded); vp out.
// 128 blocks x 256 thr, 4 rows per block.
// Qcat row (per h, 36 slots): [0..15]=qs*SS  [16..27]=2*pw_h*qp  [28..31]=0
//   [32]=-pw_h  [33]=bpb_h*PS - pw_h*q2  [34,35]=0
// Kcat row: [0..15]=ks  [16..27]=kp  [28..31]=0  [32]=k2  [33]=1  [34,35]=0
// ---------------------------------------------------------------------------
__global__ __launch_bounds__(256) void k_rot2(
    const float* __restrict__ rotm, const float* __restrict__ trans,
    const float* __restrict__ pw_in, const float* __restrict__ bpb,
    float* __restrict__ ws)
{
  __shared__ float p_l[4][288];
  __shared__ float r_l[4][288];
  __shared__ float q2_l[4][8];
  __shared__ float k2_l[4][8];
  __shared__ float pw_l[8];
  __shared__ float bpb_l[8];
  const int t = threadIdx.x;
  const int n0 = blockIdx.x * 4;
  const float* praw = ws + OFF_PRAW;
  const float* qs_g = ws + OFF_QS;
  const float* ks_g = ws + OFF_KS;

  if (t < 8) {
    float x = pw_in[t];
    pw_l[t] = 0.5f * POINT_SCALE * logf(1.0f + expf(x));
    bpb_l[t] = bpb[t];
  }
  for (int idx = t; idx < 1152; idx += 256) {
    int row = idx / 288, rem = idx % 288;
    p_l[row][rem] = praw[(size_t)(n0 + row) * 288 + rem];
  }
  __syncthreads();

  for (int idx = t; idx < 1152; idx += 256) {
    int row = idx / 288, rem = idx % 288;
    int a = rem / 96, col = rem % 96;
    int rr = col % 3;
    int n = n0 + row;
    const float* R = rotm + (size_t)(n * 3 + rr) * 3;
    const float* P = &p_l[row][a * 96 + (col - rr)];
    float val = P[0] * R[0] + P[1] * R[1] + P[2] * R[2] + trans[n * 3 + rr];
    r_l[row][a * 96 + col] = val;
    if (a == 2) (ws + OFF_VP)[(size_t)n * 96 + col] = val;
  }
  __syncthreads();

  if (t < 64) {
    int row = t >> 4, rem = t & 15;
    int which = rem >> 3, h = rem & 7;
    const float* src = &r_l[row][which * 96 + h * 12];
    float s = 0.f;
    #pragma unroll
    for (int m = 0; m < 12; ++m) s += src[m] * src[m];
    if (which == 0) q2_l[row][h] = s; else k2_l[row][h] = s;
  }
  __syncthreads();

  for (int idx = t; idx < 2304; idx += 256) {
    int side = idx >= 1152;
    int per = idx - side * 1152;
    int row = per / 288, s = per % 288;
    int h = s / 36, e = s % 36;
    int n = n0 + row;
    float val;
    if (!side) {
      val = (e < 16) ? qs_g[(size_t)n * 128 + h * 16 + e] * SCALAR_SCALE
          : (e < 28) ? 2.0f * pw_l[h] * r_l[row][h * 12 + (e - 16)]
          : (e == 32) ? -pw_l[h]
          : (e == 33) ? (bpb_l[h] * PAIR_SCALE - pw_l[h] * q2_l[row][h])
          : 0.f;
      (ws + OFF_QCAT)[(size_t)n * 288 + s] = val;
    } else {
      val = (e < 16) ? ks_g[(size_t)n * 128 + h * 16 + e]
          : (e < 28) ? r_l[row][96 + h * 12 + (e - 16)]
          : (e == 32) ? k2_l[row][h]
          : (e == 33) ? 1.f
          : 0.f;
      (ws + OFF_KCAT)[(size_t)n * 288 + s] = val;
    }
  }
}

// ---------------------------------------------------------------------------
// Kernel B1a: non-pair logits = batched GEMM lg[i,j,h] = dot36(Qcat,Kcat).
// grid (16,16): 32i x 32j tile, 2 head-groups of 4. Writes lg16[i][j][8] fp16.
// ---------------------------------------------------------------------------
__global__ __launch_bounds__(256) void k_S(
    const float* __restrict__ ws_c, __half* __restrict__ lg16)
{
  __shared__ float4 Qt[32 * 36];
  __shared__ float4 Kt[32 * 37];
  __shared__ __half lgst[32 * 32 * 8];
  const int t = threadIdx.x;
  const int it = blockIdx.x, jt = blockIdx.y;
  const float* Qc = ws_c + OFF_QCAT;
  const float* Kc = ws_c + OFF_KCAT;
  const int ti = t >> 4, tj = t & 15;

  for (int hg = 0; hg < 2; ++hg) {
    __syncthreads();
    for (int f = t; f < 1152; f += 256) {
      int row = f / 36, c = f % 36;
      Qt[row * 36 + c] = *(const float4*)&Qc[(size_t)(it * 32 + row) * 288 + hg * 144 + c * 4];
      Kt[row * 37 + c] = *(const float4*)&Kc[(size_t)(jt * 32 + row) * 288 + hg * 144 + c * 4];
    }
    __syncthreads();

    float acc[2][2][4];
    #pragma unroll
    for (int a = 0; a < 2; ++a)
      #pragma unroll
      for (int b = 0; b < 2; ++b)
        #pragma unroll
        for (int h = 0; h < 4; ++h) acc[a][b][h] = 0.f;

    for (int c = 0; c < 9; ++c) {
      #pragma unroll
      for (int hh = 0; hh < 4; ++hh) {
        float4 q0 = Qt[(2 * ti + 0) * 36 + hh * 9 + c];
        float4 q1 = Qt[(2 * ti + 1) * 36 + hh * 9 + c];
        float4 k0 = Kt[(2 * tj + 0) * 37 + hh * 9 + c];
        float4 k1 = Kt[(2 * tj + 1) * 37 + hh * 9 + c];
        acc[0][0][hh] += q0.x * k0.x + q0.y * k0.y + q0.z * k0.z + q0.w * k0.w;
        acc[0][1][hh] += q0.x * k1.x + q0.y * k1.y + q0.z * k1.z + q0.w * k1.w;
        acc[1][0][hh] += q1.x * k0.x + q1.y * k0.y + q1.z * k0.z + q1.w * k0.w;
        acc[1][1][hh] += q1.x * k1.x + q1.y * k1.y + q1.z * k1.z + q1.w * k1.w;
      }
    }
    #pragma unroll
    for (int a = 0; a < 2; ++a)
      #pragma unroll
      for (int b = 0; b < 2; ++b)
        #pragma unroll
        for (int hh = 0; hh < 4; ++hh)
          lgst[((2 * ti + a) * 32 + (2 * tj + b)) * 8 + hg * 4 + hh] = __float2half(acc[a][b][hh]);
  }
  __syncthreads();

  for (int f = t; f < 1024; f += 256) {
    int il = f >> 5, jl = f & 31;
    float4 v = *(const float4*)&lgst[(il * 32 + jl) * 8];
    *(float4*)&lg16[((size_t)(it * 32 + il) * 512 + jt * 32 + jl) * 8] = v;
  }
}

// ---------------------------------------------------------------------------
// Kernel B1b: pair logits, coalesced edge stream. grid (4 jt, 512 i).
// 16 lanes share a row; half2 shuffle reduce; RMW-add into lg16[i][j][8].
// ---------------------------------------------------------------------------
static __device__ inline __half2 shfl_xor_h2(__half2 h, int m) {
  int v = __builtin_bit_cast(int, h);
  v = __shfl_xor(v, m);
  return __builtin_bit_cast(__half2, v);
}

__global__ __launch_bounds__(256) void k_pair(
    const float* __restrict__ edge, const float* __restrict__ Wpb,
    __half* __restrict__ lg16)
{
  const int t = threadIdx.x;
  const int jt = blockIdx.x, i = blockIdx.y;
  const int l = t & 63, w = t >> 6;
  const int rg = (l >> 4) & 3, sub = l & 15;

  // per-thread Wpb slice (d = 2*sub + c + 32k), PAIR_SCALE folded
  float wv[4][2][8];
  #pragma unroll
  for (int k = 0; k < 4; ++k)
    #pragma unroll
    for (int c = 0; c < 2; ++c)
      #pragma unroll
      for (int h = 0; h < 8; ++h)
        wv[k][c][h] = Wpb[(size_t)(2 * sub + c + 32 * k) * 8 + h] * PAIR_SCALE;

  for (int p = 0; p < 8; ++p) {
    const int r = p * 16 + w * 4 + rg;
    const int j = jt * 128 + r;
    const float* eptr = edge + ((size_t)i * 512 + j) * 128 + 2 * sub;

    float2 e0 = *(const float2*)(eptr);
    float2 e1 = *(const float2*)(eptr + 32);
    float2 e2 = *(const float2*)(eptr + 64);
    float2 e3 = *(const float2*)(eptr + 96);

    float p8[8];
    #pragma unroll
    for (int h = 0; h < 8; ++h)
      p8[h] = e0.x * wv[0][0][h] + e0.y * wv[0][1][h]
            + e1.x * wv[1][0][h] + e1.y * wv[1][1][h]
            + e2.x * wv[2][0][h] + e2.y * wv[2][1][h]
            + e3.x * wv[3][0][h] + e3.y * wv[3][1][h];

    __half2 h0 = __floats2half2_rn(p8[0], p8[1]);
    __half2 h1 = __floats2half2_rn(p8[2], p8[3]);
    __half2 h2 = __floats2half2_rn(p8[4], p8[5]);
    __half2 h3 = __floats2half2_rn(p8[6], p8[7]);
    #pragma unroll
    for (int m = 1; m <= 8; m <<= 1) {
      h0 = __hadd2(h0, shfl_xor_h2(h0, m));
      h1 = __hadd2(h1, shfl_xor_h2(h1, m));
      h2 = __hadd2(h2, shfl_xor_h2(h2, m));
      h3 = __hadd2(h3, shfl_xor_h2(h3, m));
    }
    if (sub == 0) {
      __half* dst = lg16 + ((size_t)i * 512 + j) * 8;
      float4 cur = *(float4*)dst;
      __half2* ch = (__half2*)&cur;
      ch[0] = __hadd2(ch[0], h0);
      ch[1] = __hadd2(ch[1], h1);
      ch[2] = __hadd2(ch[2], h2);
      ch[3] = __hadd2(ch[3], h3);
      *(float4*)dst = cur;
    }
  }
}

// ---------------------------------------------------------------------------
// Kernel B2: softmax + all attention-weighted outputs. 512 blocks (one per i).
// ---------------------------------------------------------------------------
__global__ __launch_bounds__(256) void k_attnout(
    const float* __restrict__ edge, const float* __restrict__ rotm,
    const float* __restrict__ trans, const float* __restrict__ ws,
    const __half* __restrict__ lg16, float* __restrict__ feat)
{
  __shared__ float aw[512 * 12];
  __shared__ float pl[8 * 128 * 8];
  __shared__ float vsp[8 * 128];
  __shared__ float vpp[8 * 96];
  __shared__ float op_l[96];
  __shared__ float rp_l[96];
  __shared__ float linv_l[8];

  const int t = threadIdx.x;
  const int i = blockIdx.x;

  {
    const int lane = t & 63, wid = t >> 6;
    #pragma unroll
    for (int hh = 0; hh < 2; ++hh) {
      int h = wid * 2 + hh;
      float x[8];
      float m = -1e30f;
      #pragma unroll
      for (int r = 0; r < 8; ++r) {
        int j = lane + r * 64;
        x[r] = __half2float(lg16[((size_t)i * 512 + j) * 8 + h]);
        m = fmaxf(m, x[r]);
      }
      #pragma unroll
      for (int s = 32; s; s >>= 1) m = fmaxf(m, __shfl_xor(m, s));
      float ssum = 0.f;
      #pragma unroll
      for (int r = 0; r < 8; ++r) {
        float pv = __expf(x[r] - m);
        ssum += pv;
        aw[(lane + r * 64) * 12 + h] = pv;
      }
      #pragma unroll
      for (int s = 32; s; s >>= 1) ssum += __shfl_xor(ssum, s);
      if (lane == 0) linv_l[h] = 1.0f / ssum;
    }
  }
  __syncthreads();

  const int dq = t & 31, js = t >> 5;
  const int b = dq >> 4;
  const int c0 = dq, c1 = dq + 32, c2 = dq + 64;
  const int h0 = c0 / 12, h1 = c1 / 12, h2 = c2 / 12;

  float4 aclo[4], achi[4];
  #pragma unroll
  for (int k = 0; k < 4; ++k) { aclo[k] = {0,0,0,0}; achi[k] = {0,0,0,0}; }
  float avs[4] = {0,0,0,0};
  float avp[3] = {0,0,0};

  const float* ebase = edge + (size_t)i * 512 * 128;
  const float* vsg = ws + OFF_VS;
  const float* vpg = ws + OFF_VP;

  for (int jj = 0; jj < 64; ++jj) {
    int j = js * 64 + jj;
    const float* er = ebase + (size_t)j * 128 + dq;
    const float* vr = vsg + (size_t)j * 128 + dq;
    const float* pr = vpg + (size_t)j * 96;
    float4 wlo = *(const float4*)&aw[j * 12];
    float4 whi = *(const float4*)&aw[j * 12 + 4];
    #pragma unroll
    for (int k = 0; k < 4; ++k) {
      float e = er[32 * k];
      aclo[k].x += wlo.x * e; aclo[k].y += wlo.y * e;
      aclo[k].z += wlo.z * e; aclo[k].w += wlo.w * e;
      achi[k].x += whi.x * e; achi[k].y += whi.y * e;
      achi[k].z += whi.z * e; achi[k].w += whi.w * e;
      float vv = vr[32 * k];
      float wk = (k == 0) ? (b ? wlo.y : wlo.x)
               : (k == 1) ? (b ? wlo.w : wlo.z)
               : (k == 2) ? (b ? whi.y : whi.x)
               :            (b ? whi.w : whi.z);
      avs[k] += wk * vv;
    }
    avp[0] += aw[j * 12 + h0] * pr[c0];
    avp[1] += aw[j * 12 + h1] * pr[c1];
    avp[2] += aw[j * 12 + h2] * pr[c2];
  }

  #pragma unroll
  for (int k = 0; k < 4; ++k) {
    int d = dq + 32 * k;
    *(float4*)&pl[(js * 128 + d) * 8] = aclo[k];
    *(float4*)&pl[(js * 128 + d) * 8 + 4] = achi[k];
    vsp[js * 128 + d] = avs[k];
  }
  vpp[js * 96 + c0] = avp[0];
  vpp[js * 96 + c1] = avp[1];
  vpp[js * 96 + c2] = avp[2];
  __syncthreads();

  float* frow = feat + (size_t)i * 1280;

  {
    int d = t >> 1, hq = (t & 1) * 4;
    float4 s = {0,0,0,0};
    #pragma unroll
    for (int q = 0; q < 8; ++q) {
      float4 v = *(const float4*)&pl[(q * 128 + d) * 8 + hq];
      s.x += v.x; s.y += v.y; s.z += v.z; s.w += v.w;
    }
    frow[256 + (hq + 0) * 128 + d] = s.x * linv_l[hq + 0];
    frow[256 + (hq + 1) * 128 + d] = s.y * linv_l[hq + 1];
    frow[256 + (hq + 2) * 128 + d] = s.z * linv_l[hq + 2];
    frow[256 + (hq + 3) * 128 + d] = s.w * linv_l[hq + 3];
  }
  if (t < 128) {
    float s = 0.f;
    #pragma unroll
    for (int q = 0; q < 8; ++q) s += vsp[q * 128 + t];
    frow[t] = s * linv_l[t >> 4];
  }
  if (t < 96) {
    float s = 0.f;
    #pragma unroll
    for (int q = 0; q < 8; ++q) s += vpp[q * 96 + t];
    op_l[t] = s * linv_l[t / 12] - trans[i * 3 + (t % 3)];
  }
  __syncthreads();

  if (t < 96) {
    int c = t % 3, base = t - c;
    const float* R = rotm + (size_t)i * 9;
    float val = op_l[base] * R[c] + op_l[base + 1] * R[3 + c] + op_l[base + 2] * R[6 + c];
    rp_l[t] = val;
    frow[128 + t] = val;
  }
  __syncthreads();
  if (t < 32) {
    float x = rp_l[t * 3], y = rp_l[t * 3 + 1], z = rp_l[t * 3 + 2];
    frow[224 + t] = sqrtf(x * x + y * y + z * z + 1e-8f);
  }
}

// ---------------------------------------------------------------------------
// Kernel C1: k-split partial GEMM. grid (16, 8, 4)
// ---------------------------------------------------------------------------
__global__ __launch_bounds__(256) void k_outp(
    const float* __restrict__ feat, const float* __restrict__ Wout,
    float* __restrict__ ws)
{
  __shared__ float As[32 * 33];
  __shared__ float Bs[32 * 36];
  const int t = threadIdx.x;
  const int it = blockIdx.x, ot = blockIdx.y, z = blockIdx.z;
  const int row = t & 31, cb = (t >> 5) * 4;
  float4 acc = {0.f, 0.f, 0.f, 0.f};

  for (int kk = 0; kk < 10; ++kk) {
    int kt = z * 10 + kk;
    __syncthreads();
    #pragma unroll
    for (int q = 0; q < 4; ++q) {
      int f = t + q * 256; int r = f >> 5, c = f & 31;
      As[r * 33 + c] = feat[(size_t)(it * 32 + r) * 1280 + kt * 32 + c];
      Bs[r * 36 + c] = Wout[(size_t)(kt * 32 + r) * 256 + ot * 32 + c];
    }
    __syncthreads();
    #pragma unroll
    for (int k = 0; k < 32; ++k) {
      float a = As[row * 33 + k];
      float4 bv = *(const float4*)&Bs[k * 36 + cb];
      acc.x += a * bv.x; acc.y += a * bv.y; acc.z += a * bv.z; acc.w += a * bv.w;
    }
  }
  float* pc = ws + OFF_OUTP + (size_t)z * 131072;
  *(float4*)&pc[(size_t)(it * 32 + row) * 256 + ot * 32 + cb] = acc;
}

// ---------------------------------------------------------------------------
// Kernel C2: reduce partials + bias. grid 128 x 256.
// ---------------------------------------------------------------------------
__global__ __launch_bounds__(256) void k_outr(
    const float* __restrict__ ws, const float* __restrict__ bout,
    float* __restrict__ out)
{
  const int q = blockIdx.x * 256 + threadIdx.x;
  const float* pc = ws + OFF_OUTP;
  float4 a = *(const float4*)&pc[(size_t)q * 4];
  float4 b = *(const float4*)&pc[(size_t)q * 4 + 131072];
  float4 c = *(const float4*)&pc[(size_t)q * 4 + 262144];
  float4 d = *(const float4*)&pc[(size_t)q * 4 + 393216];
  float4 bias = *(const float4*)&bout[(q & 63) * 4];
  float4 r;
  r.x = a.x + b.x + c.x + d.x + bias.x;
  r.y = a.y + b.y + c.y + d.y + bias.y;
  r.z = a.z + b.z + c.z + d.z + bias.z;
  r.w = a.w + b.w + c.w + d.w + bias.w;
  *(float4*)&out[(size_t)q * 4] = r;
}

// ---------------------------------------------------------------------------
extern "C" void kernel_launch(void* const* d_in, const int* in_sizes, int n_in,
                              void* d_out, int out_size, void* d_ws, size_t ws_size,
                              hipStream_t stream) {
  const float* node  = (const float*)d_in[0];
  const float* edge  = (const float*)d_in[1];
  const float* rotm  = (const float*)d_in[2];
  const float* trans = (const float*)d_in[3];
  const float* Wsq   = (const float*)d_in[4];
  const float* Wsk   = (const float*)d_in[5];
  const float* Wsv   = (const float*)d_in[6];
  const float* Wpq   = (const float*)d_in[7];
  const float* Wpk   = (const float*)d_in[8];
  const float* Wpv   = (const float*)d_in[9];
  const float* pw    = (const float*)d_in[10];
  const float* Wpb   = (const float*)d_in[11];
  const float* bpb   = (const float*)d_in[12];
  const float* Wout  = (const float*)d_in[13];
  const float* bout  = (const float*)d_in[14];
  float* ws   = (float*)d_ws;
  float* out  = (float*)d_out;
  float* feat = ws + OFF_FEAT;
  __half* lg16 = (__half*)(ws + OFF_LG16);

  k_projgemm<<<dim3(16, 21), 256, 0, stream>>>(node, Wsq, Wsk, Wsv, Wpq, Wpk, Wpv, ws);
  k_rot2<<<128, 256, 0, stream>>>(rotm, trans, pw, bpb, ws);
  k_S<<<dim3(16, 16), 256, 0, stream>>>(ws, lg16);
  k_pair<<<dim3(4, 512), 256, 0, stream>>>(edge, Wpb, lg16);
  k_attnout<<<512, 256, 0, stream>>>(edge, rotm, trans, ws, lg16, feat);
  k_outp<<<dim3(16, 8, 4), 256, 0, stream>>>(feat, Wout, ws);
  k_outr<<<128, 256, 0, stream>>>(ws, bout, out);
}